// Round 6
// baseline (962.039 us; speedup 1.0000x reference)
//
#include <hip/hip_runtime.h>
#include <hip/hip_bf16.h>
#include <cstdint>

#define HWP    4096
#define CDIM   256
#define KCODES 8192
#define NROWS  32768
#define NKB    64          // 8192 / 128 code-blocks
#define LDA    72          // fp16 elems per LDS row: 64 + 8 pad -> conflict-light

typedef _Float16 f16x8 __attribute__((ext_vector_type(8)));
typedef float    f32x4 __attribute__((ext_vector_type(4)));
typedef unsigned long long u64;

// ---- sortable u64 key: (monotone f32) << 32 | (8191 - idx) -------------------
// max key == max value, ties -> smallest idx. Branch-free compare/merge.
__device__ __forceinline__ u64 key_make(float v, int idx) {
    uint32_t b = __float_as_uint(v);
    uint32_t m = (uint32_t)((int32_t)b >> 31) | 0x80000000u;
    uint32_t u = b ^ m;
    return ((u64)u << 32) | (uint32_t)(8191 - idx);
}
__device__ __forceinline__ int key_idx(u64 k) {
    return 8191 - (int)(k & 0xFFFFFFFFu);
}
// fold candidate c into running sorted pair (k1 >= k2)
__device__ __forceinline__ void fold2(u64& k1, u64& k2, u64 c) {
    u64 hi = k1 > c ? k1 : c;
    u64 lo = k1 > c ? c : k1;
    k1 = hi;
    k2 = k2 > lo ? k2 : lo;
}
// (k1,k2) = top-2 of {k1,k2,o1,o2}; inputs sorted pairs, distinct keys.
__device__ __forceinline__ void merge2(u64& k1, u64& k2, u64 o1, u64 o2) {
    u64 hi = k1 > o1 ? k1 : o1;
    u64 lo = k1 > o1 ? o1 : k1;
    u64 mx = k2 > o2 ? k2 : o2;
    k1 = hi;
    k2 = lo > mx ? lo : mx;
}
__device__ __forceinline__ void ins4(u64 c, u64 k[4]) {
    u64 a;
    a = k[0] > c ? k[0] : c;  c = k[0] > c ? c : k[0];  k[0] = a;
    a = k[1] > c ? k[1] : c;  c = k[1] > c ? c : k[1];  k[1] = a;
    a = k[2] > c ? k[2] : c;  c = k[2] > c ? c : k[2];  k[2] = a;
    k[3] = k[3] > c ? k[3] : c;
}

// =============== Kernel 1a: transpose+convert x -> xT [N][C] fp16 =============
__global__ __launch_bounds__(256) void split_x_kernel(const float* __restrict__ x,
                                                      _Float16* __restrict__ xh) {
    __shared__ float tile[64][65];
    int pb = blockIdx.x, cbk = blockIdx.y, b = blockIdx.z;
    int t = threadIdx.x;
    int p0 = pb * 64, c0 = cbk * 64;
    int pl = t & 63, cl = t >> 6;
    const float* src = x + ((size_t)b * CDIM + c0) * HWP + p0;
    #pragma unroll 4
    for (int i = 0; i < 16; ++i) {
        int c = cl * 16 + i;
        tile[c][pl] = src[(size_t)c * HWP + pl];
    }
    __syncthreads();
    int p = t >> 2, cq = (t & 3) * 16;
    size_t n = (size_t)b * HWP + p0 + p;
    alignas(16) _Float16 hbuf[16];
    #pragma unroll
    for (int j = 0; j < 16; ++j)
        hbuf[j] = (_Float16)tile[cq + j][p];
    *(int4*)(xh + n * CDIM + c0 + cq)     = ((int4*)hbuf)[0];
    *(int4*)(xh + n * CDIM + c0 + cq + 8) = ((int4*)hbuf)[1];
}

// =============== Kernel 1b: convert codebook [K][C] -> fp16 ===================
__global__ __launch_bounds__(256) void split_cb_kernel(const float* __restrict__ cb,
                                                       _Float16* __restrict__ ch) {
    int i4 = blockIdx.x * 256 + threadIdx.x;          // 2048 blocks
    float4 v = ((const float4*)cb)[i4];
    alignas(8) _Float16 h[4];
    h[0] = (_Float16)v.x; h[1] = (_Float16)v.y;
    h[2] = (_Float16)v.z; h[3] = (_Float16)v.w;
    *(uint2*)(ch + (size_t)i4 * 4) = *(uint2*)h;
}

// =============== Kernel 2: fp16 MFMA GEMM + branch-free per-(row,kb) top-2 ====
// 1D grid 16384, 256 threads = 4 waves; wave w owns rows w*32..+31 x all 128 codes.
// __launch_bounds__(256,2): 256-VGPR budget -> no scratch spill (round-5 lesson).
__global__ __launch_bounds__(256, 2) void gemm_kernel(const _Float16* __restrict__ xh,
                                                      const _Float16* __restrict__ ch,
                                                      ulonglong2* __restrict__ ptop) {
    __shared__ _Float16 sA[128 * LDA];    // 18 KB
    __shared__ _Float16 sB[128 * LDA];    // 18 KB

    int t = threadIdx.x;
    // XCD swizzle, mb fastest: B tile (64 KB) L2-hot across 32 consecutive
    // blocks; A band (2 MB/XCD) stays L2-resident across the kb sweep.
    int bid = blockIdx.x;
    int xcd = bid & 7;
    int loc = bid >> 3;              // 0..2047
    int mb  = xcd * 32 + (loc & 31);
    int kb  = loc >> 5;              // 0..63
    int n0 = mb * 128, k0 = kb * 128;
    int w = t >> 6, lane = t & 63;
    int qq = lane >> 4, cc2 = lane & 15;

    int sr = t >> 3;          // staging: row group, 32 rows per pass
    int sc = t & 7;           // 16B chunk within 128B row

    f32x4 acc[2][8];
    f32x4 zero = {0.f, 0.f, 0.f, 0.f};
    #pragma unroll
    for (int mi = 0; mi < 2; ++mi)
        #pragma unroll
        for (int ni = 0; ni < 8; ++ni) acc[mi][ni] = zero;

    for (int cs = 0; cs < CDIM; cs += 64) {
        int4 areg[4], breg[4];
        #pragma unroll
        for (int it = 0; it < 4; ++it) {
            int r = sr + it * 32;
            areg[it] = *(const int4*)(xh + (size_t)(n0 + r) * CDIM + cs + sc * 8);
            breg[it] = *(const int4*)(ch + (size_t)(k0 + r) * CDIM + cs + sc * 8);
        }
        __syncthreads();
        #pragma unroll
        for (int it = 0; it < 4; ++it) {
            int r = sr + it * 32;
            *(int4*)(sA + r * LDA + sc * 8) = areg[it];
            *(int4*)(sB + r * LDA + sc * 8) = breg[it];
        }
        __syncthreads();

        #pragma unroll
        for (int kk = 0; kk < 2; ++kk) {
            f16x8 af[2];
            #pragma unroll
            for (int mi = 0; mi < 2; ++mi) {
                int m = w * 32 + mi * 16 + cc2;
                af[mi] = *(const f16x8*)(sA + m * LDA + kk * 32 + qq * 8);
            }
            #pragma unroll
            for (int ni = 0; ni < 8; ++ni) {
                int nn = ni * 16 + cc2;
                f16x8 bf = *(const f16x8*)(sB + nn * LDA + kk * 32 + qq * 8);
                acc[0][ni] = __builtin_amdgcn_mfma_f32_16x16x32_f16(af[0], bf, acc[0][ni], 0, 0, 0);
                acc[1][ni] = __builtin_amdgcn_mfma_f32_16x16x32_f16(af[1], bf, acc[1][ni], 0, 0, 0);
            }
        }
    }

    // Epilogue: branch-free running top-2 per row (low register liveness).
    // C/D layout: col = lane&15, row = (lane>>4)*4 + reg.
    #pragma unroll
    for (int mi = 0; mi < 2; ++mi) {
        #pragma unroll
        for (int r = 0; r < 4; ++r) {
            u64 k1 = key_make(acc[mi][0][r], k0 + cc2);
            u64 k2 = 0ull;
            #pragma unroll
            for (int ni = 1; ni < 8; ++ni)
                fold2(k1, k2, key_make(acc[mi][ni][r], k0 + ni * 16 + cc2));
            #pragma unroll
            for (int msk = 1; msk <= 8; msk <<= 1) {
                u64 o1 = (u64)__shfl_xor((long long)k1, msk);
                u64 o2 = (u64)__shfl_xor((long long)k2, msk);
                merge2(k1, k2, o1, o2);
            }
            if (cc2 == 0) {
                int row = w * 32 + mi * 16 + qq * 4 + r;
                ulonglong2 e; e.x = k1; e.y = k2;
                ptop[(size_t)kb * NROWS + n0 + row] = e;
            }
        }
    }
}

// =============== Kernel 3: merge 64 k-blocks -> global top-4 candidates =======
__global__ __launch_bounds__(256) void reduce_kernel(const ulonglong2* __restrict__ ptop,
                                                     int4* __restrict__ cand) {
    int n = blockIdx.x * 256 + threadIdx.x;   // 128 blocks
    u64 k[4] = {0ull, 0ull, 0ull, 0ull};
    for (int kb = 0; kb < NKB; ++kb) {
        ulonglong2 e = ptop[(size_t)kb * NROWS + n];
        ins4(e.x, k);
        ins4(e.y, k);
    }
    cand[n] = make_int4(key_idx(k[0]), key_idx(k[1]), key_idx(k[2]), key_idx(k[3]));
}

// =============== Kernel 4: exact fp32 rescore of 4 candidates + q write + loss =
__global__ __launch_bounds__(256) void rescore_kernel(const float* __restrict__ x,
                                                      const float* __restrict__ cb,
                                                      const int4* __restrict__ cand,
                                                      float* __restrict__ out,
                                                      float* __restrict__ loss_sum) {
    int blk = blockIdx.x;                 // 512 blocks, 64 rows each
    int b = blk >> 6;
    int p0 = (blk & 63) << 6;
    int t = threadIdx.x, w = t >> 6, lane = t & 63;
    size_t rowbase = (size_t)b * HWP + p0;
    int4 cd = cand[rowbase + lane];
    const float* xb = x + (size_t)b * CDIM * HWP + p0 + lane;
    const float* c0 = cb + (size_t)cd.x * CDIM;
    const float* c1 = cb + (size_t)cd.y * CDIM;
    const float* c2 = cb + (size_t)cd.z * CDIM;
    const float* c3 = cb + (size_t)cd.w * CDIM;
    float n2 = 0.f, d0 = 0.f, d1 = 0.f, d2 = 0.f, d3 = 0.f;
    for (int c = w * 64; c < w * 64 + 64; ++c) {
        float xv = xb[(size_t)c * HWP];
        n2 = fmaf(xv, xv, n2);
        d0 = fmaf(xv, c0[c], d0);
        d1 = fmaf(xv, c1[c], d1);
        d2 = fmaf(xv, c2[c], d2);
        d3 = fmaf(xv, c3[c], d3);
    }
    __shared__ float s_n2[4][64], s_d[4][4][64];
    __shared__ int   s_win[64];
    __shared__ float s_loss[64];
    s_n2[w][lane] = n2;
    s_d[0][w][lane] = d0; s_d[1][w][lane] = d1;
    s_d[2][w][lane] = d2; s_d[3][w][lane] = d3;
    __syncthreads();
    if (t < 64) {
        float N2 = s_n2[0][t] + s_n2[1][t] + s_n2[2][t] + s_n2[3][t];
        int4 cdt = cand[rowbase + t];
        int ids[4] = {cdt.x, cdt.y, cdt.z, cdt.w};
        float bD = -3.4e38f; int bI = 0x7fffffff;
        #pragma unroll
        for (int j = 0; j < 4; ++j) {
            float D = s_d[j][0][t] + s_d[j][1][t] + s_d[j][2][t] + s_d[j][3][t];
            if (D > bD || (D == bD && ids[j] < bI)) { bD = D; bI = ids[j]; }
        }
        s_win[t]  = bI;
        s_loss[t] = bD / fmaxf(sqrtf(N2), 1e-12f);
    }
    __syncthreads();
    if (w == 0) {
        float v = s_loss[lane];
        #pragma unroll
        for (int off = 32; off; off >>= 1) v += __shfl_down(v, off);
        if (lane == 0) atomicAdd(loss_sum, v);
    }
    int win = s_win[lane];
    const float* cw = cb + (size_t)win * CDIM;
    float* ob = out + (size_t)b * CDIM * HWP + p0 + lane;
    for (int c = w * 64; c < w * 64 + 64; ++c)
        ob[(size_t)c * HWP] = cw[c];
}

// =============== Kernel 5: finalize losses ====================================
__global__ void finalize_kernel(const float* __restrict__ loss_sum,
                                float* __restrict__ out) {
    if (threadIdx.x == 0) {
        float mean = loss_sum[0] / 32768.0f;
        out[8388608] = 0.25f * (1.0f - mean);
        out[8388609] = 1.0f  * (1.0f - mean);
    }
}

extern "C" void kernel_launch(void* const* d_in, const int* in_sizes, int n_in,
                              void* d_out, int out_size, void* d_ws, size_t ws_size,
                              hipStream_t stream) {
    const float* x  = (const float*)d_in[0];   // [8,256,64,64]
    const float* cb = (const float*)d_in[1];   // [8192,256]
    float* out = (float*)d_out;

    char* ws = (char*)d_ws;
    _Float16*   xh   = (_Float16*)  (ws);                 // 16,777,216 B
    _Float16*   ch   = (_Float16*)  (ws + 16777216);      //  4,194,304 B
    ulonglong2* ptop = (ulonglong2*)(ws + 20971520);      // 33,554,432 B
    int4*       cand = (int4*)      (ws + 54525952);      //    524,288 B
    float*      loss = (float*)     (ws + 55050240);      //          4 B

    hipMemsetAsync(loss, 0, 4, stream);
    split_x_kernel <<<dim3(64, 4, 8), 256, 0, stream>>>(x, xh);
    split_cb_kernel<<<2048,           256, 0, stream>>>(cb, ch);
    gemm_kernel    <<<16384,          256, 0, stream>>>(xh, ch, ptop);
    reduce_kernel  <<<128,            256, 0, stream>>>(ptop, cand);
    rescore_kernel <<<512,            256, 0, stream>>>(x, cb, cand, out, loss);
    finalize_kernel<<<1,              64,  0, stream>>>(loss, out);
}

// Round 7
// 506.695 us; speedup vs baseline: 1.8987x; 1.8987x over previous
//
#include <hip/hip_runtime.h>
#include <hip/hip_bf16.h>
#include <cstdint>

#define HWP    4096
#define CDIM   256
#define KCODES 8192
#define NROWS  32768
#define NKB    64          // 8192 / 128 code-blocks

typedef _Float16 f16x8 __attribute__((ext_vector_type(8)));
typedef float    f32x4 __attribute__((ext_vector_type(4)));
typedef unsigned long long u64;

// ---- async global->LDS, 16B per lane; LDS dest = wave-uniform base + lane*16 ----
__device__ __forceinline__ void load16_to_lds(const void* g, void* s) {
    __builtin_amdgcn_global_load_lds(
        (const __attribute__((address_space(1))) void*)(uintptr_t)g,
        (__attribute__((address_space(3))) void*)(uintptr_t)s,
        16, 0, 0);
}

// ---- sortable u64 key: (monotone f32) << 32 | (8191 - idx) -------------------
// max key == max value, ties -> smallest idx. Branch-free compare/merge.
__device__ __forceinline__ u64 key_make(float v, int idx) {
    uint32_t b = __float_as_uint(v);
    uint32_t m = (uint32_t)((int32_t)b >> 31) | 0x80000000u;
    uint32_t u = b ^ m;
    return ((u64)u << 32) | (uint32_t)(8191 - idx);
}
__device__ __forceinline__ int key_idx(u64 k) {
    return 8191 - (int)(k & 0xFFFFFFFFu);
}
// fold candidate c into running sorted pair (k1 >= k2)
__device__ __forceinline__ void fold2(u64& k1, u64& k2, u64 c) {
    u64 hi = k1 > c ? k1 : c;
    u64 lo = k1 > c ? c : k1;
    k1 = hi;
    k2 = k2 > lo ? k2 : lo;
}
// (k1,k2) = top-2 of {k1,k2,o1,o2}; inputs sorted pairs, distinct keys.
__device__ __forceinline__ void merge2(u64& k1, u64& k2, u64 o1, u64 o2) {
    u64 hi = k1 > o1 ? k1 : o1;
    u64 lo = k1 > o1 ? o1 : k1;
    u64 mx = k2 > o2 ? k2 : o2;
    k1 = hi;
    k2 = lo > mx ? lo : mx;
}
__device__ __forceinline__ void ins4(u64 c, u64 k[4]) {
    u64 a;
    a = k[0] > c ? k[0] : c;  c = k[0] > c ? c : k[0];  k[0] = a;
    a = k[1] > c ? k[1] : c;  c = k[1] > c ? c : k[1];  k[1] = a;
    a = k[2] > c ? k[2] : c;  c = k[2] > c ? c : k[2];  k[2] = a;
    k[3] = k[3] > c ? k[3] : c;
}

// =============== Kernel 1a: transpose+convert x -> xT [N][C] fp16 =============
__global__ __launch_bounds__(256) void split_x_kernel(const float* __restrict__ x,
                                                      _Float16* __restrict__ xh) {
    __shared__ float tile[64][65];
    int pb = blockIdx.x, cbk = blockIdx.y, b = blockIdx.z;
    int t = threadIdx.x;
    int p0 = pb * 64, c0 = cbk * 64;
    int pl = t & 63, cl = t >> 6;
    const float* src = x + ((size_t)b * CDIM + c0) * HWP + p0;
    #pragma unroll 4
    for (int i = 0; i < 16; ++i) {
        int c = cl * 16 + i;
        tile[c][pl] = src[(size_t)c * HWP + pl];
    }
    __syncthreads();
    int p = t >> 2, cq = (t & 3) * 16;
    size_t n = (size_t)b * HWP + p0 + p;
    alignas(16) _Float16 hbuf[16];
    #pragma unroll
    for (int j = 0; j < 16; ++j)
        hbuf[j] = (_Float16)tile[cq + j][p];
    *(int4*)(xh + n * CDIM + c0 + cq)     = ((int4*)hbuf)[0];
    *(int4*)(xh + n * CDIM + c0 + cq + 8) = ((int4*)hbuf)[1];
}

// =============== Kernel 1b: convert codebook [K][C] -> fp16 ===================
__global__ __launch_bounds__(256) void split_cb_kernel(const float* __restrict__ cb,
                                                       _Float16* __restrict__ ch) {
    int i4 = blockIdx.x * 256 + threadIdx.x;          // 2048 blocks
    float4 v = ((const float4*)cb)[i4];
    alignas(8) _Float16 h[4];
    h[0] = (_Float16)v.x; h[1] = (_Float16)v.y;
    h[2] = (_Float16)v.z; h[3] = (_Float16)v.w;
    *(uint2*)(ch + (size_t)i4 * 4) = *(uint2*)h;
}

// =============== Kernel 2: fp16 MFMA GEMM + branch-free per-(row,kb) top-2 ====
// 1D grid 16384, 256 threads = 4 waves; wave w owns rows w*32..+31 x all 128 codes.
// Staging: global_load_lds (direct to LDS, zero barrier-crossing VGPR liveness)
// with XOR-swizzled rows (slot c8 holds global c8^(r&7)) -> conflict-free reads.
__global__ __launch_bounds__(256) void gemm_kernel(const _Float16* __restrict__ xh,
                                                   const _Float16* __restrict__ ch,
                                                   ulonglong2* __restrict__ ptop) {
    __shared__ _Float16 sA[128 * 64];     // 16 KB
    __shared__ _Float16 sB[128 * 64];     // 16 KB

    int t = threadIdx.x;
    // XCD swizzle, mb fastest: B tile (64 KB) L2-hot across 32 consecutive
    // blocks; A band (2 MB/XCD) stays L2-resident across the kb sweep.
    int bid = blockIdx.x;
    int xcd = bid & 7;
    int loc = bid >> 3;              // 0..2047
    int mb  = xcd * 32 + (loc & 31);
    int kb  = loc >> 5;              // 0..63
    int n0 = mb * 128, k0 = kb * 128;
    int w = t >> 6, lane = t & 63;
    int qq = lane >> 4, cc2 = lane & 15;

    // Staging geometry: chunk = it*256 + t; row r = chunk>>3; LDS slot c8 = chunk&7
    // holds global col-group c8 ^ (r&7). Per-instr LDS dest is wave-uniform.
    int aoff[4], boff[4];
    #pragma unroll
    for (int it = 0; it < 4; ++it) {
        int chk = it * 256 + t;
        int r   = chk >> 3;
        int sw  = (chk & 7) ^ (r & 7);
        aoff[it] = (n0 + r) * CDIM + sw * 8;
        boff[it] = (k0 + r) * CDIM + sw * 8;
    }

    f32x4 acc[2][8];
    f32x4 zero = {0.f, 0.f, 0.f, 0.f};
    #pragma unroll
    for (int mi = 0; mi < 2; ++mi)
        #pragma unroll
        for (int ni = 0; ni < 8; ++ni) acc[mi][ni] = zero;

    for (int cs = 0; cs < CDIM; cs += 64) {
        __syncthreads();
        #pragma unroll
        for (int it = 0; it < 4; ++it) {
            unsigned lo = (unsigned)((it * 256 + w * 64) * 16) >> 1;  // bytes: chunk*16, in fp16 elems *8
            load16_to_lds(xh + aoff[it] + cs, (char*)sA + (size_t)lo * 2);
            load16_to_lds(ch + boff[it] + cs, (char*)sB + (size_t)lo * 2);
        }
        __syncthreads();

        #pragma unroll
        for (int kk = 0; kk < 2; ++kk) {
            f16x8 af[2];
            #pragma unroll
            for (int mi = 0; mi < 2; ++mi) {
                int m  = w * 32 + mi * 16 + cc2;
                int c8 = ((kk << 2) | qq) ^ (m & 7);
                af[mi] = *(const f16x8*)((const char*)sA + m * 128 + c8 * 16);
            }
            #pragma unroll
            for (int ni = 0; ni < 8; ++ni) {
                int nn = ni * 16 + cc2;
                int c8 = ((kk << 2) | qq) ^ (nn & 7);
                f16x8 bf = *(const f16x8*)((const char*)sB + nn * 128 + c8 * 16);
                acc[0][ni] = __builtin_amdgcn_mfma_f32_16x16x32_f16(af[0], bf, acc[0][ni], 0, 0, 0);
                acc[1][ni] = __builtin_amdgcn_mfma_f32_16x16x32_f16(af[1], bf, acc[1][ni], 0, 0, 0);
            }
        }
    }

    // Epilogue: branch-free running top-2 per row (low register liveness).
    // C/D layout: col = lane&15, row = (lane>>4)*4 + reg.
    #pragma unroll
    for (int mi = 0; mi < 2; ++mi) {
        #pragma unroll
        for (int r = 0; r < 4; ++r) {
            u64 k1 = key_make(acc[mi][0][r], k0 + cc2);
            u64 k2 = 0ull;
            #pragma unroll
            for (int ni = 1; ni < 8; ++ni)
                fold2(k1, k2, key_make(acc[mi][ni][r], k0 + ni * 16 + cc2));
            #pragma unroll
            for (int msk = 1; msk <= 8; msk <<= 1) {
                u64 o1 = (u64)__shfl_xor((long long)k1, msk);
                u64 o2 = (u64)__shfl_xor((long long)k2, msk);
                merge2(k1, k2, o1, o2);
            }
            if (cc2 == 0) {
                int row = w * 32 + mi * 16 + qq * 4 + r;
                ulonglong2 e; e.x = k1; e.y = k2;
                ptop[(size_t)kb * NROWS + n0 + row] = e;
            }
        }
    }
}

// =============== Kernel 3: merge 64 k-blocks -> global top-4 candidates =======
__global__ __launch_bounds__(256) void reduce_kernel(const ulonglong2* __restrict__ ptop,
                                                     int4* __restrict__ cand) {
    int n = blockIdx.x * 256 + threadIdx.x;   // 128 blocks
    u64 k[4] = {0ull, 0ull, 0ull, 0ull};
    for (int kb = 0; kb < NKB; ++kb) {
        ulonglong2 e = ptop[(size_t)kb * NROWS + n];
        ins4(e.x, k);
        ins4(e.y, k);
    }
    cand[n] = make_int4(key_idx(k[0]), key_idx(k[1]), key_idx(k[2]), key_idx(k[3]));
}

// =============== Kernel 4: exact fp32 rescore of 4 candidates + q write + loss =
__global__ __launch_bounds__(256) void rescore_kernel(const float* __restrict__ x,
                                                      const float* __restrict__ cb,
                                                      const int4* __restrict__ cand,
                                                      float* __restrict__ out,
                                                      float* __restrict__ loss_sum) {
    int blk = blockIdx.x;                 // 512 blocks, 64 rows each
    int b = blk >> 6;
    int p0 = (blk & 63) << 6;
    int t = threadIdx.x, w = t >> 6, lane = t & 63;
    size_t rowbase = (size_t)b * HWP + p0;
    int4 cd = cand[rowbase + lane];
    const float* xb = x + (size_t)b * CDIM * HWP + p0 + lane;
    const float* c0 = cb + (size_t)cd.x * CDIM;
    const float* c1 = cb + (size_t)cd.y * CDIM;
    const float* c2 = cb + (size_t)cd.z * CDIM;
    const float* c3 = cb + (size_t)cd.w * CDIM;
    float n2 = 0.f, d0 = 0.f, d1 = 0.f, d2 = 0.f, d3 = 0.f;
    for (int c = w * 64; c < w * 64 + 64; ++c) {
        float xv = xb[(size_t)c * HWP];
        n2 = fmaf(xv, xv, n2);
        d0 = fmaf(xv, c0[c], d0);
        d1 = fmaf(xv, c1[c], d1);
        d2 = fmaf(xv, c2[c], d2);
        d3 = fmaf(xv, c3[c], d3);
    }
    __shared__ float s_n2[4][64], s_d[4][4][64];
    __shared__ int   s_win[64];
    __shared__ float s_loss[64];
    s_n2[w][lane] = n2;
    s_d[0][w][lane] = d0; s_d[1][w][lane] = d1;
    s_d[2][w][lane] = d2; s_d[3][w][lane] = d3;
    __syncthreads();
    if (t < 64) {
        float N2 = s_n2[0][t] + s_n2[1][t] + s_n2[2][t] + s_n2[3][t];
        int4 cdt = cand[rowbase + t];
        int ids[4] = {cdt.x, cdt.y, cdt.z, cdt.w};
        float bD = -3.4e38f; int bI = 0x7fffffff;
        #pragma unroll
        for (int j = 0; j < 4; ++j) {
            float D = s_d[j][0][t] + s_d[j][1][t] + s_d[j][2][t] + s_d[j][3][t];
            if (D > bD || (D == bD && ids[j] < bI)) { bD = D; bI = ids[j]; }
        }
        s_win[t]  = bI;
        s_loss[t] = bD / fmaxf(sqrtf(N2), 1e-12f);
    }
    __syncthreads();
    if (w == 0) {
        float v = s_loss[lane];
        #pragma unroll
        for (int off = 32; off; off >>= 1) v += __shfl_down(v, off);
        if (lane == 0) atomicAdd(loss_sum, v);
    }
    int win = s_win[lane];
    const float* cw = cb + (size_t)win * CDIM;
    float* ob = out + (size_t)b * CDIM * HWP + p0 + lane;
    for (int c = w * 64; c < w * 64 + 64; ++c)
        ob[(size_t)c * HWP] = cw[c];
}

// =============== Kernel 5: finalize losses ====================================
__global__ void finalize_kernel(const float* __restrict__ loss_sum,
                                float* __restrict__ out) {
    if (threadIdx.x == 0) {
        float mean = loss_sum[0] / 32768.0f;
        out[8388608] = 0.25f * (1.0f - mean);
        out[8388609] = 1.0f  * (1.0f - mean);
    }
}

extern "C" void kernel_launch(void* const* d_in, const int* in_sizes, int n_in,
                              void* d_out, int out_size, void* d_ws, size_t ws_size,
                              hipStream_t stream) {
    const float* x  = (const float*)d_in[0];   // [8,256,64,64]
    const float* cb = (const float*)d_in[1];   // [8192,256]
    float* out = (float*)d_out;

    char* ws = (char*)d_ws;
    _Float16*   xh   = (_Float16*)  (ws);                 // 16,777,216 B
    _Float16*   ch   = (_Float16*)  (ws + 16777216);      //  4,194,304 B
    ulonglong2* ptop = (ulonglong2*)(ws + 20971520);      // 33,554,432 B
    int4*       cand = (int4*)      (ws + 54525952);      //    524,288 B
    float*      loss = (float*)     (ws + 55050240);      //          4 B

    hipMemsetAsync(loss, 0, 4, stream);
    split_x_kernel <<<dim3(64, 4, 8), 256, 0, stream>>>(x, xh);
    split_cb_kernel<<<2048,           256, 0, stream>>>(cb, ch);
    gemm_kernel    <<<16384,          256, 0, stream>>>(xh, ch, ptop);
    reduce_kernel  <<<128,            256, 0, stream>>>(ptop, cand);
    rescore_kernel <<<512,            256, 0, stream>>>(x, cb, cand, out, loss);
    finalize_kernel<<<1,              64,  0, stream>>>(loss, out);
}

// Round 8
// 417.029 us; speedup vs baseline: 2.3069x; 1.2150x over previous
//
#include <hip/hip_runtime.h>
#include <hip/hip_bf16.h>
#include <cstdint>

#define HWP    4096
#define CDIM   256
#define KCODES 8192
#define NROWS  32768
#define NKB    64          // 8192 / 128 code-blocks

typedef _Float16 f16x8 __attribute__((ext_vector_type(8)));
typedef float    f32x4 __attribute__((ext_vector_type(4)));
typedef unsigned long long u64;

// ---- async global->LDS, 16B per lane; LDS dest = wave-uniform base + lane*16 ----
__device__ __forceinline__ void load16_to_lds(const void* g, void* s) {
    __builtin_amdgcn_global_load_lds(
        (const __attribute__((address_space(1))) void*)(uintptr_t)g,
        (__attribute__((address_space(3))) void*)(uintptr_t)s,
        16, 0, 0);
}

// u64 branch-free top-4 insert (for the tiny reduce kernel)
__device__ __forceinline__ void ins4(u64 c, u64 k[4]) {
    u64 a;
    a = k[0] > c ? k[0] : c;  c = k[0] > c ? c : k[0];  k[0] = a;
    a = k[1] > c ? k[1] : c;  c = k[1] > c ? c : k[1];  k[1] = a;
    a = k[2] > c ? k[2] : c;  c = k[2] > c ? c : k[2];  k[2] = a;
    k[3] = k[3] > c ? k[3] : c;
}

// =============== Kernel 1a: transpose x -> xh fp16 [N][C] + xt fp32 [N][C] ====
__global__ __launch_bounds__(256) void split_x_kernel(const float* __restrict__ x,
                                                      _Float16* __restrict__ xh,
                                                      float* __restrict__ xt) {
    __shared__ float tile[64][65];
    int pb = blockIdx.x, cbk = blockIdx.y, b = blockIdx.z;
    int t = threadIdx.x;
    int p0 = pb * 64, c0 = cbk * 64;
    int pl = t & 63, cl = t >> 6;
    const float* src = x + ((size_t)b * CDIM + c0) * HWP + p0;
    #pragma unroll 4
    for (int i = 0; i < 16; ++i) {
        int c = cl * 16 + i;
        tile[c][pl] = src[(size_t)c * HWP + pl];
    }
    __syncthreads();
    int p = t >> 2, cq = (t & 3) * 16;
    size_t n = (size_t)b * HWP + p0 + p;
    alignas(16) _Float16 hbuf[16];
    alignas(16) float    fbuf[16];
    #pragma unroll
    for (int j = 0; j < 16; ++j) {
        float v = tile[cq + j][p];
        fbuf[j] = v;
        hbuf[j] = (_Float16)v;
    }
    *(int4*)(xh + n * CDIM + c0 + cq)     = ((int4*)hbuf)[0];
    *(int4*)(xh + n * CDIM + c0 + cq + 8) = ((int4*)hbuf)[1];
    #pragma unroll
    for (int j = 0; j < 4; ++j)
        *(float4*)(xt + n * CDIM + c0 + cq + j * 4) = ((float4*)fbuf)[j];
}

// =============== Kernel 1b: convert codebook [K][C] -> fp16 ===================
__global__ __launch_bounds__(256) void split_cb_kernel(const float* __restrict__ cb,
                                                       _Float16* __restrict__ ch) {
    int i4 = blockIdx.x * 256 + threadIdx.x;          // 2048 blocks
    float4 v = ((const float4*)cb)[i4];
    alignas(8) _Float16 h[4];
    h[0] = (_Float16)v.x; h[1] = (_Float16)v.y;
    h[2] = (_Float16)v.z; h[3] = (_Float16)v.w;
    *(uint2*)(ch + (size_t)i4 * 4) = *(uint2*)h;
}

// =============== Kernel 2: fp16 MFMA GEMM + u32-key per-(row,kb) top-2 ========
// 1D grid 16384, 256 threads = 4 waves; wave w owns rows w*32..+31 x all 128 codes.
// Key: bits(v+2048) is monotone; for v+2048 in (1024,4096) the top 7 bits are
// constant, so key = (u<<7)|tag is a LOSSLESS u32 ordering. tag = inv(ni),inv(cc2)
// (7 bits) lets the reduce kernel reconstruct the code id. |v|<=256 by Cauchy-
// Schwarz, so the range precondition always holds. Exactness of the approx
// ordering is not required anyway (exact top-4 rescore downstream).
__global__ __launch_bounds__(256) void gemm_kernel(const _Float16* __restrict__ xh,
                                                   const _Float16* __restrict__ ch,
                                                   uint2* __restrict__ ptop) {
    __shared__ _Float16 sA[128 * 64];     // 16 KB, XOR-swizzled rows
    __shared__ _Float16 sB[128 * 64];     // 16 KB

    int t = threadIdx.x;
    // XCD swizzle, mb fastest: B tile L2-hot across 32 consecutive blocks;
    // A band (2 MB/XCD) stays L2-resident across the kb sweep.
    int bid = blockIdx.x;
    int xcd = bid & 7;
    int loc = bid >> 3;              // 0..2047
    int mb  = xcd * 32 + (loc & 31);
    int kb  = loc >> 5;              // 0..63
    int n0 = mb * 128, k0 = kb * 128;
    int w = t >> 6, lane = t & 63;
    int qq = lane >> 4, cc2 = lane & 15;
    uint32_t inv_cc2 = (uint32_t)(15 - cc2);

    // Staging geometry: chunk = it*256 + t; row r = chunk>>3; LDS slot c8 = chunk&7
    // holds global col-group c8 ^ (r&7). Per-instr LDS dest is wave-uniform.
    int aoff[4], boff[4];
    #pragma unroll
    for (int it = 0; it < 4; ++it) {
        int chk = it * 256 + t;
        int r   = chk >> 3;
        int sw  = (chk & 7) ^ (r & 7);
        aoff[it] = (n0 + r) * CDIM + sw * 8;
        boff[it] = (k0 + r) * CDIM + sw * 8;
    }

    f32x4 acc[2][8];
    f32x4 zero = {0.f, 0.f, 0.f, 0.f};
    #pragma unroll
    for (int mi = 0; mi < 2; ++mi)
        #pragma unroll
        for (int ni = 0; ni < 8; ++ni) acc[mi][ni] = zero;

    for (int cs = 0; cs < CDIM; cs += 64) {
        __syncthreads();
        #pragma unroll
        for (int it = 0; it < 4; ++it) {
            unsigned lo = (unsigned)((it * 256 + w * 64) * 16);   // bytes
            load16_to_lds(xh + aoff[it] + cs, (char*)sA + lo);
            load16_to_lds(ch + boff[it] + cs, (char*)sB + lo);
        }
        __syncthreads();

        #pragma unroll
        for (int kk = 0; kk < 2; ++kk) {
            f16x8 af[2];
            #pragma unroll
            for (int mi = 0; mi < 2; ++mi) {
                int m  = w * 32 + mi * 16 + cc2;
                int c8 = ((kk << 2) | qq) ^ (m & 7);
                af[mi] = *(const f16x8*)((const char*)sA + m * 128 + c8 * 16);
            }
            #pragma unroll
            for (int ni = 0; ni < 8; ++ni) {
                int nn = ni * 16 + cc2;
                int c8 = ((kk << 2) | qq) ^ (nn & 7);
                f16x8 bf = *(const f16x8*)((const char*)sB + nn * 128 + c8 * 16);
                acc[0][ni] = __builtin_amdgcn_mfma_f32_16x16x32_f16(af[0], bf, acc[0][ni], 0, 0, 0);
                acc[1][ni] = __builtin_amdgcn_mfma_f32_16x16x32_f16(af[1], bf, acc[1][ni], 0, 0, 0);
            }
        }
    }

    // Epilogue: u32-key branch-free top-2 per row over 128 codes.
    // C/D layout: col = lane&15, row = (lane>>4)*4 + reg.
    #pragma unroll
    for (int mi = 0; mi < 2; ++mi) {
        #pragma unroll
        for (int r = 0; r < 4; ++r) {
            uint32_t k1 = 0u, k2 = 0u;
            #pragma unroll
            for (int ni = 0; ni < 8; ++ni) {
                uint32_t tag = ((uint32_t)((7 - ni) << 4)) | inv_cc2;
                uint32_t u   = __float_as_uint(acc[mi][ni][r] + 2048.0f);
                uint32_t key = (u << 7) | tag;
                uint32_t hi = k1 > key ? k1 : key;
                uint32_t lo = k1 > key ? key : k1;
                k1 = hi;
                k2 = k2 > lo ? k2 : lo;
            }
            #pragma unroll
            for (int msk = 1; msk <= 8; msk <<= 1) {
                uint32_t o1 = (uint32_t)__shfl_xor((int)k1, msk);
                uint32_t o2 = (uint32_t)__shfl_xor((int)k2, msk);
                uint32_t hi = k1 > o1 ? k1 : o1;
                uint32_t lo = k1 > o1 ? o1 : k1;
                uint32_t t2 = k2 > o2 ? k2 : o2;
                k1 = hi;
                k2 = lo > t2 ? lo : t2;
            }
            if (cc2 == 0) {
                int row = w * 32 + mi * 16 + qq * 4 + r;
                ptop[(size_t)kb * NROWS + n0 + row] = make_uint2(k1, k2);
            }
        }
    }
}

// =============== Kernel 3: merge 64 k-blocks -> global top-4 code ids =========
__global__ __launch_bounds__(256) void reduce_kernel(const uint2* __restrict__ ptop,
                                                     int4* __restrict__ cand) {
    int n = blockIdx.x * 256 + threadIdx.x;   // 128 blocks
    u64 k[4] = {0ull, 0ull, 0ull, 0ull};
    for (int kb = 0; kb < NKB; ++kb) {
        uint2 e = ptop[(size_t)kb * NROWS + n];
        ins4(((u64)e.x << 6) | (unsigned)kb, k);
        ins4(((u64)e.y << 6) | (unsigned)kb, k);
    }
    int code[4];
    #pragma unroll
    for (int j = 0; j < 4; ++j) {
        int kbc      = (int)(k[j] & 63u);
        uint32_t key = (uint32_t)(k[j] >> 6);
        int ni       = 7  - (int)((key >> 4) & 7u);
        int c2       = 15 - (int)(key & 15u);
        code[j] = kbc * 128 + ni * 16 + c2;
    }
    cand[n] = make_int4(code[0], code[1], code[2], code[3]);
}

// =============== Kernel 4: exact fp32 rescore (coalesced) -> winner idx + loss =
// 2048 blocks, 256 threads; 16 lanes per row -> 16 rows per block.
__global__ __launch_bounds__(256) void rescore_kernel(const float* __restrict__ xt,
                                                      const float* __restrict__ cb,
                                                      const int4* __restrict__ cand,
                                                      int* __restrict__ widx,
                                                      float* __restrict__ loss_sum) {
    int t = threadIdx.x, l = t & 63;
    int cl = t & 15;
    int n = blockIdx.x * 16 + (t >> 4);
    int4 cd = cand[n];
    const float* xr = xt + (size_t)n * CDIM + cl * 16;
    const float* r0 = cb + (size_t)cd.x * CDIM + cl * 16;
    const float* r1 = cb + (size_t)cd.y * CDIM + cl * 16;
    const float* r2 = cb + (size_t)cd.z * CDIM + cl * 16;
    const float* r3 = cb + (size_t)cd.w * CDIM + cl * 16;
    float n2 = 0.f, d0 = 0.f, d1 = 0.f, d2 = 0.f, d3 = 0.f;
    #pragma unroll
    for (int chk = 0; chk < 4; ++chk) {
        float4 xv = *(const float4*)(xr + chk * 4);
        float4 a0 = *(const float4*)(r0 + chk * 4);
        float4 a1 = *(const float4*)(r1 + chk * 4);
        float4 a2 = *(const float4*)(r2 + chk * 4);
        float4 a3 = *(const float4*)(r3 + chk * 4);
        float xs[4] = {xv.x, xv.y, xv.z, xv.w};
        float b0[4] = {a0.x, a0.y, a0.z, a0.w};
        float b1[4] = {a1.x, a1.y, a1.z, a1.w};
        float b2[4] = {a2.x, a2.y, a2.z, a2.w};
        float b3[4] = {a3.x, a3.y, a3.z, a3.w};
        #pragma unroll
        for (int j = 0; j < 4; ++j) {
            n2 = fmaf(xs[j], xs[j], n2);
            d0 = fmaf(xs[j], b0[j], d0);
            d1 = fmaf(xs[j], b1[j], d1);
            d2 = fmaf(xs[j], b2[j], d2);
            d3 = fmaf(xs[j], b3[j], d3);
        }
    }
    #pragma unroll
    for (int m = 1; m <= 8; m <<= 1) {
        n2 += __shfl_xor(n2, m);
        d0 += __shfl_xor(d0, m);
        d1 += __shfl_xor(d1, m);
        d2 += __shfl_xor(d2, m);
        d3 += __shfl_xor(d3, m);
    }
    float lp = 0.f;
    if (cl == 0) {
        float bD = d0; int bI = cd.x;
        if (d1 > bD || (d1 == bD && cd.y < bI)) { bD = d1; bI = cd.y; }
        if (d2 > bD || (d2 == bD && cd.z < bI)) { bD = d2; bI = cd.z; }
        if (d3 > bD || (d3 == bD && cd.w < bI)) { bD = d3; bI = cd.w; }
        widx[n] = bI;
        lp = bD / fmaxf(sqrtf(n2), 1e-12f);
    }
    #pragma unroll
    for (int m = 1; m <= 32; m <<= 1) lp += __shfl_xor(lp, m);
    if (l == 0) atomicAdd(loss_sum, lp);
}

// =============== Kernel 5: gather q via LDS transpose + coalesced write + loss =
__global__ __launch_bounds__(256) void writeq_kernel(const float* __restrict__ cb,
                                                     const int* __restrict__ widx,
                                                     const float* __restrict__ loss_sum,
                                                     float* __restrict__ out) {
    __shared__ float rows[64][260];       // pad 260 (16B-aligned rows)
    int bh = blockIdx.x;                  // b*64 + h, 512 blocks
    int b = bh >> 6, h = bh & 63;
    int t = threadIdx.x;
    int rr = t >> 6, cq = t & 63;
    #pragma unroll 4
    for (int i = 0; i < 16; ++i) {
        int wv = i * 4 + rr;
        int id = widx[bh * 64 + wv];
        float4 v = *(const float4*)(cb + (size_t)id * CDIM + cq * 4);
        *(float4*)&rows[wv][cq * 4] = v;
    }
    __syncthreads();
    int wl = t & 63, cg = t >> 6;
    float* ob = out + (size_t)b * CDIM * HWP + h * 64 + wl;
    #pragma unroll 4
    for (int c = cg * 64; c < cg * 64 + 64; ++c)
        ob[(size_t)c * HWP] = rows[wl][c];
    if (bh == 0 && t == 0) {
        float mean = loss_sum[0] / 32768.0f;
        out[8388608] = 0.25f * (1.0f - mean);
        out[8388609] = 1.0f  * (1.0f - mean);
    }
}

extern "C" void kernel_launch(void* const* d_in, const int* in_sizes, int n_in,
                              void* d_out, int out_size, void* d_ws, size_t ws_size,
                              hipStream_t stream) {
    const float* x  = (const float*)d_in[0];   // [8,256,64,64]
    const float* cb = (const float*)d_in[1];   // [8192,256]
    float* out = (float*)d_out;

    char* ws = (char*)d_ws;
    _Float16* xh   = (_Float16*)(ws);                     // 16,777,216 B
    _Float16* ch   = (_Float16*)(ws + 16777216);          //  4,194,304 B
    float*    xt   = (float*)   (ws + 20971520);          // 33,554,432 B
    uint2*    ptop = (uint2*)   (ws + 54525952);          // 16,777,216 B
    int4*     cand = (int4*)    (ws + 71303168);          //    524,288 B
    int*      widx = (int*)     (ws + 71827456);          //    131,072 B
    float*    loss = (float*)   (ws + 71958528);          //          4 B

    hipMemsetAsync(loss, 0, 4, stream);
    split_x_kernel <<<dim3(64, 4, 8), 256, 0, stream>>>(x, xh, xt);
    split_cb_kernel<<<2048,           256, 0, stream>>>(cb, ch);
    gemm_kernel    <<<16384,          256, 0, stream>>>(xh, ch, ptop);
    reduce_kernel  <<<128,            256, 0, stream>>>(ptop, cand);
    rescore_kernel <<<2048,           256, 0, stream>>>(xt, cb, cand, widx, loss);
    writeq_kernel  <<<512,            256, 0, stream>>>(cb, widx, loss, out);
}